// Round 10
// baseline (102.383 us; speedup 1.0000x reference)
//
#include <hip/hip_runtime.h>

// DurationEncoding: idx = searchsorted(bin_edges, time_value, 'left'); out = embed_table[idx]
// N=1M, NUM_EDGES=100, VOCAB=101, DIM=128, fp32. Write-BW-bound (537 MB out; write-ideal ~81 us).
//
// R10: wave-autonomous variant of R8. Each 64-lane wave owns 64 rows:
// lane searches 1 row; emission fetches the row offset from the owning lane
// via __shfl (ds_bpermute) instead of LDS s_off. No phase barriers -> waves
// stream stores independently (fill-kernel-like), memory pipe never drains
// at block phase boundaries. Table reads go through L1/L2 (R9 showed LDS
// staging of the table is a net loss).

#define MAX_EDGES 128
#define PAD_INF 3.402823466e+38f

typedef float vfloat4 __attribute__((ext_vector_type(4)));

__device__ __forceinline__ int lb128(const float* s_edges, float v) {
    int lo = 0;
    #pragma unroll
    for (int step = 64; step > 0; step >>= 1)
        if (s_edges[lo + step - 1] < v) lo += step;   // branchless lower_bound, 128 padded
    return lo;
}

// ---------- R10 kernel: DIM=128 (32 float4/row), 64 rows/wave, 256 rows/block ----------
__global__ __launch_bounds__(256) void duration_encoding_wave(
    const float* __restrict__ time_value,
    const float* __restrict__ bin_edges,
    const float* __restrict__ embed_table,
    float* __restrict__ out,
    unsigned int n, int num_edges)
{
    __shared__ float s_edges[MAX_EDGES];
    if (threadIdx.x < MAX_EDGES)
        s_edges[threadIdx.x] = (threadIdx.x < (unsigned)num_edges)
                                   ? bin_edges[threadIdx.x] : PAD_INF;
    __syncthreads();                                   // only barrier (edges staging)

    const unsigned int lane  = threadIdx.x & 63u;
    const unsigned int wbase = blockIdx.x * 256u + ((threadIdx.x >> 6) << 6); // wave's first row

    // one search per lane (row wbase+lane)
    unsigned int r = wbase + lane;
    float v = (r < n) ? time_value[r] : 0.0f;
    int my_off = lb128(s_edges, v) << 5;               // pre-scaled row offset (f4 units)

    const vfloat4* t4 = (const vfloat4*)embed_table;
    vfloat4* o4 = (vfloat4*)out;
    const unsigned int base4 = wbase << 5;

    if (wbase + 64u <= n) {                            // fast path
        #pragma unroll 8
        for (int k = 0; k < 32; ++k) {
            // lanes 0-31 emit row 2k, lanes 32-63 emit row 2k+1
            int src  = (k << 1) + (int)(lane >> 5);
            int roff = __shfl(my_off, src, 64);        // ds_bpermute from owning lane
            // j = base4 + k*64 + lane -> 1KB contiguous per wave store
            o4[base4 + ((unsigned)k << 6) + lane] = t4[roff + (int)(lane & 31u)];
        }
    } else if (wbase < n) {                            // guarded tail wave
        unsigned int rows = n - wbase;                 // 1..63
        for (unsigned int k = 0; k < 32u; ++k) {
            unsigned int row = (k << 1) + (lane >> 5);
            int roff = __shfl(my_off, (int)row, 64);
            if (row < rows)
                o4[base4 + (k << 6) + lane] = t4[roff + (int)(lane & 31u)];
        }
    }
}

// ---------- Generic fallback (any DIM % 4 == 0) ----------
__device__ __forceinline__ int lower_bound_lds(const float* s_edges, int num_edges, float v) {
    int lo = 0, hi = num_edges;
    while (lo < hi) {
        int mid = (lo + hi) >> 1;
        if (s_edges[mid] < v) lo = mid + 1; else hi = mid;
    }
    return lo;
}

__global__ __launch_bounds__(256) void duration_encoding_generic(
    const float* __restrict__ time_value,
    const float* __restrict__ bin_edges,
    const float* __restrict__ embed_table,
    float* __restrict__ out,
    unsigned int n, int num_edges, unsigned int f4_per_row)
{
    __shared__ float s_edges[MAX_EDGES];
    for (int i = threadIdx.x; i < num_edges; i += blockDim.x)
        s_edges[i] = bin_edges[i];
    __syncthreads();

    const unsigned long long total  = (unsigned long long)n * f4_per_row;
    const unsigned long long stride = (unsigned long long)gridDim.x * blockDim.x;
    const float4* table4 = (const float4*)embed_table;
    float4* out4 = (float4*)out;

    for (unsigned long long j = (unsigned long long)blockIdx.x * blockDim.x + threadIdx.x;
         j < total; j += stride) {
        unsigned int row = (unsigned int)(j / f4_per_row);
        unsigned int c4  = (unsigned int)(j - (unsigned long long)row * f4_per_row);
        float v = time_value[row];
        int lo = lower_bound_lds(s_edges, num_edges, v);
        out4[j] = table4[(unsigned long long)lo * f4_per_row + c4];
    }
}

extern "C" void kernel_launch(void* const* d_in, const int* in_sizes, int n_in,
                              void* d_out, int out_size, void* d_ws, size_t ws_size,
                              hipStream_t stream) {
    const float* time_value  = (const float*)d_in[0];
    const float* bin_edges   = (const float*)d_in[1];
    const float* embed_table = (const float*)d_in[2];
    float* out = (float*)d_out;

    const unsigned int n         = (unsigned int)in_sizes[0];
    const int          num_edges = in_sizes[1];
    const unsigned int dim       = (unsigned int)(out_size / in_sizes[0]);
    const unsigned int f4_per_row = dim / 4;

    const int block = 256;

    if (f4_per_row == 32u && num_edges <= MAX_EDGES) {
        unsigned int grid = (n + 255u) / 256u;
        duration_encoding_wave<<<(int)grid, block, 0, stream>>>(
            time_value, bin_edges, embed_table, out, n, num_edges);
    } else {
        const unsigned long long total = (unsigned long long)n * f4_per_row;
        unsigned long long bn = (total + block - 1) / block;
        int grid = (int)(bn < 2048ull ? bn : 2048ull);
        duration_encoding_generic<<<grid, block, 0, stream>>>(
            time_value, bin_edges, embed_table, out, n, num_edges, f4_per_row);
    }
}

// Round 11
// 100.497 us; speedup vs baseline: 1.0188x; 1.0188x over previous
//
#include <hip/hip_runtime.h>

// DurationEncoding: idx = searchsorted(bin_edges, time_value, 'left'); out = embed_table[idx]
// N=1M, NUM_EDGES=100, VOCAB=101, DIM=128, fp32. Write-BW-bound (537 MB out; write-ideal ~81 us).
//
// R11 = revert to R8 (best measured: 100.3 us). Fused kernel, 512 rows/block,
// two interleaved searches/thread, LDS s_off, plain (cached) float4 stores.
// Dead-end log: nt stores (-3), LDS-staged table (-2), barrier-free wave
// emission (-2), idx-in-ws round trip (-5), per-f4 redundant search (-34).

#define MAX_EDGES 128
#define PAD_INF 3.402823466e+38f
#define ROWS_PER_BLOCK 512

typedef float vfloat4 __attribute__((ext_vector_type(4)));

// ---------- Fused kernel, DIM=128 (32 float4/row), 512 rows/block ----------
__global__ __launch_bounds__(256) void duration_encoding_fused(
    const float* __restrict__ time_value,
    const float* __restrict__ bin_edges,
    const float* __restrict__ embed_table,
    float* __restrict__ out,
    unsigned int n, int num_edges)
{
    __shared__ float s_edges[MAX_EDGES];
    __shared__ int   s_off[ROWS_PER_BLOCK];           // pre-scaled: idx*32 (float4 units)

    if (threadIdx.x < MAX_EDGES)
        s_edges[threadIdx.x] = (threadIdx.x < (unsigned)num_edges)
                                   ? bin_edges[threadIdx.x] : PAD_INF;
    __syncthreads();

    const unsigned int base = blockIdx.x * ROWS_PER_BLOCK;

    // ---- Phase 1: two searches per thread (independent chains, ILP) ----
    {
        unsigned int r0 = base + threadIdx.x;
        unsigned int r1 = base + 256u + threadIdx.x;
        float v0 = (r0 < n) ? time_value[r0] : 0.0f;
        float v1 = (r1 < n) ? time_value[r1] : 0.0f;
        int lo0 = 0, lo1 = 0;
        #pragma unroll
        for (int step = 64; step > 0; step >>= 1) {   // interleaved: 2 LDS reads in flight
            if (s_edges[lo0 + step - 1] < v0) lo0 += step;
            if (s_edges[lo1 + step - 1] < v1) lo1 += step;
        }
        s_off[threadIdx.x]        = lo0 << 5;
        s_off[threadIdx.x + 256]  = lo1 << 5;
    }
    __syncthreads();

    // ---- Phase 2: emit 512 rows as 64 coalesced 1KB/wave iterations ----
    const vfloat4* t4 = (const vfloat4*)embed_table;
    vfloat4* o4 = (vfloat4*)out;
    const unsigned int base4 = base << 5;             // block's first float4 index

    if (base + ROWS_PER_BLOCK <= n) {                 // fast path (no guards)
        #pragma unroll 8
        for (int k = 0; k < 64; ++k) {
            unsigned int j = ((unsigned int)k << 8) + threadIdx.x;  // 0..16383
            int roff = s_off[j >> 5];
            o4[base4 + j] = t4[roff + (int)(j & 31u)];
        }
    } else {                                          // guarded tail block
        unsigned int limit = (n - base) << 5;
        for (unsigned int j = threadIdx.x; j < limit; j += blockDim.x) {
            int roff = s_off[j >> 5];
            o4[base4 + j] = t4[roff + (int)(j & 31u)];
        }
    }
}

// ---------- Generic fallback (any DIM % 4 == 0) ----------
__device__ __forceinline__ int lower_bound_lds(const float* s_edges, int num_edges, float v) {
    int lo = 0, hi = num_edges;
    while (lo < hi) {
        int mid = (lo + hi) >> 1;
        if (s_edges[mid] < v) lo = mid + 1; else hi = mid;
    }
    return lo;
}

__global__ __launch_bounds__(256) void duration_encoding_generic(
    const float* __restrict__ time_value,
    const float* __restrict__ bin_edges,
    const float* __restrict__ embed_table,
    float* __restrict__ out,
    unsigned int n, int num_edges, unsigned int f4_per_row)
{
    __shared__ float s_edges[MAX_EDGES];
    for (int i = threadIdx.x; i < num_edges; i += blockDim.x)
        s_edges[i] = bin_edges[i];
    __syncthreads();

    const unsigned long long total  = (unsigned long long)n * f4_per_row;
    const unsigned long long stride = (unsigned long long)gridDim.x * blockDim.x;
    const float4* table4 = (const float4*)embed_table;
    float4* out4 = (float4*)out;

    for (unsigned long long j = (unsigned long long)blockIdx.x * blockDim.x + threadIdx.x;
         j < total; j += stride) {
        unsigned int row = (unsigned int)(j / f4_per_row);
        unsigned int c4  = (unsigned int)(j - (unsigned long long)row * f4_per_row);
        float v = time_value[row];
        int lo = lower_bound_lds(s_edges, num_edges, v);
        out4[j] = table4[(unsigned long long)lo * f4_per_row + c4];
    }
}

extern "C" void kernel_launch(void* const* d_in, const int* in_sizes, int n_in,
                              void* d_out, int out_size, void* d_ws, size_t ws_size,
                              hipStream_t stream) {
    const float* time_value  = (const float*)d_in[0];
    const float* bin_edges   = (const float*)d_in[1];
    const float* embed_table = (const float*)d_in[2];
    float* out = (float*)d_out;

    const unsigned int n         = (unsigned int)in_sizes[0];
    const int          num_edges = in_sizes[1];
    const unsigned int dim       = (unsigned int)(out_size / in_sizes[0]);
    const unsigned int f4_per_row = dim / 4;

    const int block = 256;

    if (f4_per_row == 32u && num_edges <= MAX_EDGES) {
        unsigned int grid = (n + ROWS_PER_BLOCK - 1) / ROWS_PER_BLOCK;
        duration_encoding_fused<<<(int)grid, block, 0, stream>>>(
            time_value, bin_edges, embed_table, out, n, num_edges);
    } else {
        const unsigned long long total = (unsigned long long)n * f4_per_row;
        unsigned long long bn = (total + block - 1) / block;
        int grid = (int)(bn < 2048ull ? bn : 2048ull);
        duration_encoding_generic<<<grid, block, 0, stream>>>(
            time_value, bin_edges, embed_table, out, n, num_edges, f4_per_row);
    }
}